// Round 9
// baseline (38.355 us; speedup 1.0000x reference)
//
#include <hip/hip_runtime.h>

// KeypointPostProcessor: B=256, Q=2048, K=17, C=51 channels per row.
// NOTE: harness delivers the bool padding_mask as int32.
//
// R4 (46.9us): grid-stride, per-unit global param loads + predicated recompute.
// R6/R7 (50.5/49.8us): ILP on the OLD structure regressed (param recompute inflation).
// R8 (37.6us): block=256 rows; per-row params once into 8KB LDS; masked rows as
//   all-zero params (lim=0 clips to 0; scores in [0,1) pass via lim>=64).
//   VALU 21%, HBM 4.3/6.3 TB/s -> issue/latency-bound, neither pipe saturated.
// R9: single change vs R8 -> Phase B unrolled x2 (units u and u+256, loads
//   hoisted, stores last). Cheap units make ILP viable now.

namespace {

constexpr unsigned ROWS_PER_BLOCK  = 256;
constexpr unsigned CCH             = 51;                      // 3*K
constexpr unsigned XYCH            = 34;                      // 2*K
constexpr unsigned UNITS_PER_BLOCK = ROWS_PER_BLOCK * CCH / 4; // 3264 (exact)

__device__ __forceinline__ float4 compute_unit(
    unsigned u, float4 v, const float4 (*__restrict__ P)[2])
{
    const unsigned e = u * 4u;
    unsigned rl = e / CCH;                  // magic-divide, local row 0..255
    unsigned c  = e - rl * CCH;
    float4 p0 = P[rl][0];                   // {x1, y1, bw, bh}
    float4 p1 = P[rl][1];                   // {iw, ih, 0, 0}

    float in[4] = {v.x, v.y, v.z, v.w};
    float o[4];
#pragma unroll
    for (int j = 0; j < 4; ++j) {
        if (c == CCH) {                     // row crossing: cheap LDS reload
            c = 0u;
            ++rl;
            p0 = P[rl][0];
            p1 = P[rl][1];
        }
        const bool odd = (c & 1u) != 0u;
        const bool xy  = c < XYCH;
        const float scale = xy ? (odd ? p0.w : p0.z) : 1.0f;
        const float off   = xy ? (odd ? p0.y : p0.x) : 0.0f;
        const float lim   = odd ? p1.y : p1.x;
        o[j] = fminf(fmaxf(fmaf(in[j], scale, off), 0.0f), lim);
        ++c;
    }
    return make_float4(o[0], o[1], o[2], o[3]);
}

} // namespace

__global__ __launch_bounds__(256) void kp_post_kernel(
    const float4* __restrict__ pred4,
    const float4* __restrict__ boxes4,
    const int*    __restrict__ mask,
    const int2*   __restrict__ sizes2,
    float4* __restrict__ out4)
{
    // P[r][0] = {x1, y1, bw, bh};  P[r][1] = {iw, ih, 0, 0}
    __shared__ float4 P[ROWS_PER_BLOCK][2];

    const unsigned tid  = threadIdx.x;
    const unsigned row0 = blockIdx.x * ROWS_PER_BLOCK;

    // ---- Phase A: one thread per row, params computed once ----
    {
        const unsigned row = row0 + tid;
        const int2 hw = sizes2[row >> 11];
        const int h = hw.x, w = hw.y;
        const int mx = h > w ? h : w;
        const float left = (float)((mx - w) >> 1);
        const float top  = (float)((mx - h) >> 1);
        const float ms = (float)mx;
        const float iw = (float)w;
        const float ih = (float)h;
        const float4 bx = boxes4[row];
        const float x1 = fminf(fmaxf((bx.x - 0.5f * bx.z) * ms - left, 0.0f), iw);
        const float y1 = fminf(fmaxf((bx.y - 0.5f * bx.w) * ms - top , 0.0f), ih);
        const float x2 = fminf(fmaxf((bx.x + 0.5f * bx.z) * ms - left, 0.0f), iw);
        const float y2 = fminf(fmaxf((bx.y + 0.5f * bx.w) * ms - top , 0.0f), ih);
        const float z = (mask[row] != 0) ? 0.0f : 1.0f;   // masked row -> all params 0
        P[tid][0] = make_float4(x1 * z, y1 * z, (x2 - x1) * z, (y2 - y1) * z);
        P[tid][1] = make_float4(iw * z, ih * z, 0.0f, 0.0f);
    }
    __syncthreads();

    // ---- Phase B: 2-way unrolled sweep of the block's contiguous region ----
    const unsigned base4 = blockIdx.x * UNITS_PER_BLOCK;
    unsigned u = tid;
    for (; u + 256u < UNITS_PER_BLOCK; u += 512u) {
        const unsigned uB = u + 256u;
        const float4 vA = pred4[base4 + u];
        const float4 vB = pred4[base4 + uB];
        const float4 oA = compute_unit(u,  vA, P);
        const float4 oB = compute_unit(uB, vB, P);
        out4[base4 + u]  = oA;
        out4[base4 + uB] = oB;
    }
    if (u < UNITS_PER_BLOCK) {              // 192-unit tail (tid < 192)
        const float4 vA = pred4[base4 + u];
        out4[base4 + u] = compute_unit(u, vA, P);
    }
}

extern "C" void kernel_launch(void* const* d_in, const int* in_sizes, int n_in,
                              void* d_out, int out_size, void* d_ws, size_t ws_size,
                              hipStream_t stream) {
    const float4* pred4  = (const float4*)d_in[0];
    const float4* boxes4 = (const float4*)d_in[1];
    const int*    mask   = (const int*)d_in[2];
    const int2*   sizes2 = (const int2*)d_in[3];
    float4* out4 = (float4*)d_out;

    const unsigned total = (unsigned)out_size;        // 26,738,688
    const unsigned rows  = total / (3u * 17u);        // 524,288
    const int grid = (int)(rows / ROWS_PER_BLOCK);    // 2048, exact

    hipLaunchKernelGGL(kp_post_kernel, dim3(grid), dim3(256), 0, stream,
                       pred4, boxes4, mask, sizes2, out4);
}

// Round 10
// 37.820 us; speedup vs baseline: 1.0141x; 1.0141x over previous
//
#include <hip/hip_runtime.h>

// KeypointPostProcessor: B=256, Q=2048, K=17, C=51 channels per row.
// NOTE: harness delivers the bool padding_mask as int32.
//
// R4 (46.9us): grid-stride, per-unit global param loads + predicated recompute.
// R6/R7 (50.5/49.8us): ILP on the OLD structure regressed.
// R8 (37.6us): block=256 rows; per-row params once into 8KB LDS; masked rows as
//   all-zero params. VALU 21%, HBM 4.3/6.3 TB/s, Occ 69%.
// R9 (38.4us): ILP x2 on R8 -> flat (3rd null ILP result; not latency-starved).
// R10: R8 exact + single change: nontemporal stores (bypass L2/L3 write-
//   allocate so the 104MB dead output stream stops evicting L3-resident pred).

namespace {

typedef float vfloat4 __attribute__((ext_vector_type(4)));

constexpr unsigned ROWS_PER_BLOCK  = 256;
constexpr unsigned CCH             = 51;                      // 3*K
constexpr unsigned XYCH            = 34;                      // 2*K
constexpr unsigned UNITS_PER_BLOCK = ROWS_PER_BLOCK * CCH / 4; // 3264 (exact)

} // namespace

__global__ __launch_bounds__(256) void kp_post_kernel(
    const float4* __restrict__ pred4,
    const float4* __restrict__ boxes4,
    const int*    __restrict__ mask,
    const int2*   __restrict__ sizes2,
    vfloat4* __restrict__ out4)
{
    // P[r][0] = {x1, y1, bw, bh};  P[r][1] = {iw, ih, 0, 0}
    __shared__ float4 P[ROWS_PER_BLOCK][2];

    const unsigned tid  = threadIdx.x;
    const unsigned row0 = blockIdx.x * ROWS_PER_BLOCK;

    // ---- Phase A: one thread per row, params computed once ----
    {
        const unsigned row = row0 + tid;
        const int2 hw = sizes2[row >> 11];
        const int h = hw.x, w = hw.y;
        const int mx = h > w ? h : w;
        const float left = (float)((mx - w) >> 1);
        const float top  = (float)((mx - h) >> 1);
        const float ms = (float)mx;
        const float iw = (float)w;
        const float ih = (float)h;
        const float4 bx = boxes4[row];
        const float x1 = fminf(fmaxf((bx.x - 0.5f * bx.z) * ms - left, 0.0f), iw);
        const float y1 = fminf(fmaxf((bx.y - 0.5f * bx.w) * ms - top , 0.0f), ih);
        const float x2 = fminf(fmaxf((bx.x + 0.5f * bx.z) * ms - left, 0.0f), iw);
        const float y2 = fminf(fmaxf((bx.y + 0.5f * bx.w) * ms - top , 0.0f), ih);
        const float z = (mask[row] != 0) ? 0.0f : 1.0f;   // masked row -> all params 0
        P[tid][0] = make_float4(x1 * z, y1 * z, (x2 - x1) * z, (y2 - y1) * z);
        P[tid][1] = make_float4(iw * z, ih * z, 0.0f, 0.0f);
    }
    __syncthreads();

    // ---- Phase B: sweep the block's contiguous region ----
    const unsigned base4 = blockIdx.x * UNITS_PER_BLOCK;
    for (unsigned u = tid; u < UNITS_PER_BLOCK; u += 256u) {
        const unsigned t = base4 + u;
        const float4 v = pred4[t];

        const unsigned e = u * 4u;
        unsigned rl = e / CCH;                  // magic-divide, local row 0..255
        unsigned c  = e - rl * CCH;
        float4 p0 = P[rl][0];
        float4 p1 = P[rl][1];

        float in[4] = {v.x, v.y, v.z, v.w};
        vfloat4 o;
#pragma unroll
        for (int j = 0; j < 4; ++j) {
            if (c == CCH) {                     // row crossing: cheap LDS reload
                c = 0u;
                ++rl;
                p0 = P[rl][0];
                p1 = P[rl][1];
            }
            const bool odd = (c & 1u) != 0u;
            const bool xy  = c < XYCH;
            const float scale = xy ? (odd ? p0.w : p0.z) : 1.0f;
            const float off   = xy ? (odd ? p0.y : p0.x) : 0.0f;
            const float lim   = odd ? p1.y : p1.x;
            o[j] = fminf(fmaxf(fmaf(in[j], scale, off), 0.0f), lim);
            ++c;
        }
        __builtin_nontemporal_store(o, &out4[t]);
    }
}

extern "C" void kernel_launch(void* const* d_in, const int* in_sizes, int n_in,
                              void* d_out, int out_size, void* d_ws, size_t ws_size,
                              hipStream_t stream) {
    const float4* pred4  = (const float4*)d_in[0];
    const float4* boxes4 = (const float4*)d_in[1];
    const int*    mask   = (const int*)d_in[2];
    const int2*   sizes2 = (const int2*)d_in[3];
    vfloat4* out4 = (vfloat4*)d_out;

    const unsigned total = (unsigned)out_size;        // 26,738,688
    const unsigned rows  = total / (3u * 17u);        // 524,288
    const int grid = (int)(rows / ROWS_PER_BLOCK);    // 2048, exact

    hipLaunchKernelGGL(kp_post_kernel, dim3(grid), dim3(256), 0, stream,
                       pred4, boxes4, mask, sizes2, out4);
}